// Round 25
// baseline (20.090 us; speedup 1.0000x reference)
//
#include <hip/hip_runtime.h>
#include <hip/hip_bf16.h>

// MoE: out[b] = inp[b] @ weight[gate[b]].T
// inp: [4096,512] f32, gate: [4096] int, weight: [32,512,512] f32, out: [4096,512] f32
// Round 25: r24 (best correct, 18.75us) with BN=128: 4 n-tiles instead of 8 ->
// A-panel re-reads through L2 halve (~64MB -> ~32MB) and MFMA per sync event
// doubles (16/wave/iter). Grid 384 (%8==0, bijective XCD swizzle, same expert
// locality). LDS 48KB -> 3 blocks/CU (the measured risk vs r24's 4).
// Rest r24-verbatim: BK=64 double-buffer, ONE drain+barrier/iter (race-free by
// disjoint buffers + full lgkm drain), mask prep (2 barriers, hoisted shfl),
// W tile-0 pre-prep issue, pinned pre-COMPUTE loads, 16B ds_writes, XOR swizzle,
// TMAX=3, clamped pad rows.

#define NE     32
#define NBATCH 4096
#define KF     512
#define NF     512
#define BM     64
#define BN     128
#define BK     64
#define NKT    (KF / BK)     // 8
#define TMAX   3
#define NCHUNK 64
#define NWG    (4 * NE * TMAX)  // 384, %8==0 -> bijective XCD swizzle
#define BUFB   ((BM + BN) * BK * 2)  // 24KB per buffer (A 8KB + W 16KB)

typedef __attribute__((ext_vector_type(8))) short bf16x8;
typedef __attribute__((ext_vector_type(4))) float f32x4;

__device__ __forceinline__ unsigned cvt2(float lo, float hi) {
    __hip_bfloat162 h = __float22bfloat162_rn(make_float2(lo, hi));
    return *reinterpret_cast<unsigned*>(&h);   // v_cvt_pk_bf16_f32
}

// XOR swizzle within [row][64 bf16] (128B row stride); same bijection write+read.
__device__ __forceinline__ int swz(int row, int col_b) {
    return row * 128 + (col_b ^ ((row & 7) << 4));
}

__global__ __launch_bounds__(256)
void moe_fused(const float* __restrict__ inp,
               const int* __restrict__ gate,
               const float* __restrict__ weight,
               float* __restrict__ out) {
    // bijective XCD-chunk swizzle (384 blocks, 8 XCDs, 48/chunk): XCD k owns
    // experts [4k,4k+4) -> W panels + token rows pinned in that L2.
    const int bid = blockIdx.x;
    const int swb = (bid & 7) * (NWG / 8) + (bid >> 3);
    const int nb    = swb & 3;           // 4 n-tiles
    const int y     = swb >> 2;          // 0..95
    const int e     = y / 3;
    const int local = y - e * 3;

    __shared__ __align__(16) unsigned char lds[2 * BUFB];  // 48KB double buffer
    __shared__ int srow[BM];
    __shared__ int chunkinfo[NCHUNK];

    const int tid  = threadIdx.x;
    const int lane = tid & 63;
    const int wid  = tid >> 6;

    // staging map (16B granule): A rows (tid>>3)+32*i (i<2); W rows (tid>>3)+32*i
    // (i<4); float col (tid&7)*8 (16 consecutive bf16 after cvt).
    const int srow_r = tid >> 3;         // 0..31
    const int c8     = (tid & 7) * 8;    // float offset of first float4
    const int nblk   = nb * BN;
    const float* wbase = weight + (size_t)e * (NF * KF) + (size_t)nblk * KF;

    float4 ra[4], rw[8];                 // [2i],[2i+1] = row-slot i's two float4s

    // ---- W tile-0 issued BEFORE prep: only needs e; latency hides under prep ----
#pragma unroll
    for (int i = 0; i < 4; ++i) {
        int r = srow_r + 32 * i;
        rw[2 * i]     = *(const float4*)(wbase + (size_t)r * KF + c8);
        rw[2 * i + 1] = *(const float4*)(wbase + (size_t)r * KF + c8 + 4);
    }
    asm volatile("" ::: "memory");       // pin: issue now, don't sink into prep

    // ---- self-prep: int4 gate loads + mask rank + per-wave redundant scan ----
    // thread owns gates [tid*16, tid*16+16), all inside chunk tid>>2
    int4 gv[4];
#pragma unroll
    for (int j = 0; j < 4; ++j)
        gv[j] = ((const int4*)gate)[tid * 4 + j];

    unsigned mask = 0;
#pragma unroll
    for (int j = 0; j < 4; ++j) {
        if (gv[j].x == e) mask |= 1u << (j * 4 + 0);
        if (gv[j].y == e) mask |= 1u << (j * 4 + 1);
        if (gv[j].z == e) mask |= 1u << (j * 4 + 2);
        if (gv[j].w == e) mask |= 1u << (j * 4 + 3);
    }
    const int cnt = __popc(mask);

    // inclusive scan over the 4 threads of this chunk (lanes grouped by 4)
    int xs = cnt;
    {
        int u = __shfl_up(xs, 1, 4); if ((lane & 3) >= 1) xs += u;
        u     = __shfl_up(xs, 2, 4); if ((lane & 3) >= 2) xs += u;
    }
    const int pre = xs - cnt;            // exclusive prefix within chunk
    if ((lane & 3) == 3) chunkinfo[tid >> 2] = xs;   // chunk total
    if (tid < BM) srow[tid] = -1;
    __syncthreads();                     // barrier 1: chunk counts + srow init

    // per-wave redundant scan of all 64 chunk counts (no wave-0 serialization)
    int cc = chunkinfo[lane];
    int x  = cc;
#pragma unroll
    for (int d = 1; d < 64; d <<= 1) {
        int u = __shfl_up(x, d, 64);
        if (lane >= d) x += u;
    }
    const int excl  = x - cc;            // lane l holds exclusive base of chunk l
    const int total = __shfl(x, 63, 64);

    // shfl with ALL lanes active (r18 bug fix: inactive source = undefined)
    const int chunkbase = __shfl(excl, tid >> 2, 64);

    const int m0 = local * BM;
    if (m0 >= total) return;             // block-uniform exit (no barrier pending)

    // scatter: rank = own-chunk base + within-chunk prefix + intra-thread order
    if (mask) {
        int rr = chunkbase + pre;
        unsigned mm = mask;
        while (mm) {
            int j = __ffs(mm) - 1;
            mm &= mm - 1;
            if (rr >= m0 && rr < m0 + BM)
                srow[rr - m0] = tid * 16 + j;
            ++rr;
        }
    }
    __syncthreads();                     // barrier 2: srow ready

    const int wm = wid & 1;              // 2 m-halves (32 rows)
    const int wn = wid >> 1;             // 2 n-halves (64 cols)

    int arow[2];
    const float* ap[2];
#pragma unroll
    for (int i = 0; i < 2; ++i) {
        arow[i] = srow[srow_r + 32 * i];
        // clamp pad rows to row 0: real data, outputs never stored (r14-validated)
        ap[i] = inp + (size_t)(arow[i] < 0 ? 0 : arow[i]) * KF + c8;
    }

#define LOADA(T) do { const int k0 = (T) * BK;                                       \
    _Pragma("unroll") for (int i = 0; i < 2; ++i) {                                  \
        ra[2 * i]     = *(const float4*)(ap[i] + k0);                                \
        ra[2 * i + 1] = *(const float4*)(ap[i] + k0 + 4); } } while (0)

#define LOADW(T) do { const int k0 = (T) * BK;                                       \
    _Pragma("unroll") for (int i = 0; i < 4; ++i) {                                  \
        int r = srow_r + 32 * i;                                                     \
        rw[2 * i]     = *(const float4*)(wbase + (size_t)r * KF + k0 + c8);          \
        rw[2 * i + 1] = *(const float4*)(wbase + (size_t)r * KF + k0 + c8 + 4); } } while (0)

#define WRITE_TILE(B) do { const int cb = (tid & 7) * 16;                            \
    unsigned char* Lb = lds + (B) * BUFB;                                            \
    _Pragma("unroll") for (int i = 0; i < 2; ++i) {                                  \
        int r = srow_r + 32 * i;                                                     \
        uint4 p = make_uint4(cvt2(ra[2*i].x,   ra[2*i].y),                           \
                             cvt2(ra[2*i].z,   ra[2*i].w),                           \
                             cvt2(ra[2*i+1].x, ra[2*i+1].y),                         \
                             cvt2(ra[2*i+1].z, ra[2*i+1].w));                        \
        *(uint4*)(Lb + swz(r, cb)) = p; }                                            \
    _Pragma("unroll") for (int i = 0; i < 4; ++i) {                                  \
        int r = srow_r + 32 * i;                                                     \
        uint4 p = make_uint4(cvt2(rw[2*i].x,   rw[2*i].y),                           \
                             cvt2(rw[2*i].z,   rw[2*i].w),                           \
                             cvt2(rw[2*i+1].x, rw[2*i+1].y),                         \
                             cvt2(rw[2*i+1].z, rw[2*i+1].w));                        \
        *(uint4*)(Lb + 8192 + swz(r, cb)) = p; } } while (0)

    f32x4 acc[2][4];
#pragma unroll
    for (int mi = 0; mi < 2; ++mi)
#pragma unroll
        for (int ni = 0; ni < 4; ++ni) acc[mi][ni] = (f32x4)(0.f);

#define COMPUTE(B) do { const unsigned char* Lb = lds + (B) * BUFB;                  \
    _Pragma("unroll") for (int kk = 0; kk < 2; ++kk) {                               \
        const int kb = kk * 64 + 16 * (lane >> 4);                                   \
        bf16x8 af[2], bfr[4];                                                        \
        _Pragma("unroll") for (int mi = 0; mi < 2; ++mi) {                           \
            int r = wm * 32 + mi * 16 + (lane & 15);                                 \
            af[mi] = *(const bf16x8*)(Lb + swz(r, kb)); }                            \
        _Pragma("unroll") for (int ni = 0; ni < 4; ++ni) {                           \
            int r = wn * 64 + ni * 16 + (lane & 15);                                 \
            bfr[ni] = *(const bf16x8*)(Lb + 8192 + swz(r, kb)); }                    \
        _Pragma("unroll") for (int mi = 0; mi < 2; ++mi)                             \
        _Pragma("unroll") for (int ni = 0; ni < 4; ++ni)                             \
            acc[mi][ni] = __builtin_amdgcn_mfma_f32_16x16x32_bf16(                   \
                af[mi], bfr[ni], acc[mi][ni], 0, 0, 0); } } while (0)

    // ---- double-buffered K-loop: ONE drain+barrier per iteration ----
    // Race-freedom (r24-validated): reads of buf X (iter t) drain at iter t's
    // end-barrier; the next write to buf X is at iter t+1, after that barrier.
    LOADA(0);                            // W tile 0 in flight since kernel entry
    asm volatile("" ::: "memory");
    WRITE_TILE(0);                       // vmcnt waits tile-0 loads only
    asm volatile("s_waitcnt lgkmcnt(0)" ::: "memory");
    __builtin_amdgcn_s_barrier();        // buf0 ready

    for (int t = 0; t < NKT; ++t) {
        if (t + 1 < NKT) {
            LOADA(t + 1);                // issue early: COMPUTE covers latency
            LOADW(t + 1);
            asm volatile("" ::: "memory");  // PIN: loads may not sink below
        }
        COMPUTE(t & 1);                  // reads buf[cur]
        if (t + 1 < NKT) {
            WRITE_TILE((t + 1) & 1);     // disjoint buf: overlaps MFMA stream
            asm volatile("s_waitcnt lgkmcnt(0)" ::: "memory");  // reads+writes
            __builtin_amdgcn_s_barrier();
        }
    }
#undef LOADA
#undef LOADW
#undef WRITE_TILE
#undef COMPUTE

    // ---- epilogue: D frag col=lane&15 (n), row=(lane>>4)*4+q (m) ----
#pragma unroll
    for (int mi = 0; mi < 2; ++mi)
#pragma unroll
        for (int q = 0; q < 4; ++q) {
            int m = wm * 32 + mi * 16 + (lane >> 4) * 4 + q;
            int row = srow[m];
            if (row >= 0) {
#pragma unroll
                for (int ni = 0; ni < 4; ++ni)
                    out[(size_t)row * NF + nblk + wn * 64 + ni * 16 + (lane & 15)]
                        = acc[mi][ni][q];
            }
        }
}

extern "C" void kernel_launch(void* const* d_in, const int* in_sizes, int n_in,
                              void* d_out, int out_size, void* d_ws, size_t ws_size,
                              hipStream_t stream) {
    const float* inp    = (const float*)d_in[0];
    const int*   gate   = (const int*)d_in[1];
    const float* weight = (const float*)d_in[2];
    float*       out    = (float*)d_out;

    moe_fused<<<NWG, 256, 0, stream>>>(inp, gate, weight, out);
}

// Round 26
// 18.682 us; speedup vs baseline: 1.0754x; 1.0754x over previous
//
#include <hip/hip_runtime.h>
#include <hip/hip_bf16.h>

// MoE: out[b] = inp[b] @ weight[gate[b]].T
// inp: [4096,512] f32, gate: [4096] int, weight: [32,512,512] f32, out: [4096,512] f32
// Round 26: r24 (best correct, 18.75us) at 512 threads / 8 waves -- the untested
// axis. Same 64x64x64 double-buffered tile, same ONE drain+barrier/iter schedule;
// per-wave work halves (wave tile 16x64, 4 MFMA + 6 ds_read/iter), per-thread
// staging halves. 24-32 waves/CU vs r24's 12-16: tests whether wave-level TLP
// (the confirmed hiding mechanism) was capped by wave slots.
// Prep adapted: 8 gates/thread, 8-lane segment scan, chunk=tid>>3; chunkbase
// shfl is within-wave (tid>>3 = wid*8+(lane>>3) <= 63, every wave has the full
// redundant 64-chunk scan). All r24-validated parts otherwise verbatim.

#define NE     32
#define NBATCH 4096
#define KF     512
#define NF     512
#define BM     64
#define BN     64
#define BK     64
#define NKT    (KF / BK)     // 8
#define TMAX   3
#define NCHUNK 64
#define NWG    (8 * NE * TMAX)  // 768, %8==0 -> bijective XCD swizzle
#define BUFB   ((BM + BN) * BK * 2)  // 16KB per buffer

typedef __attribute__((ext_vector_type(8))) short bf16x8;
typedef __attribute__((ext_vector_type(4))) float f32x4;

__device__ __forceinline__ unsigned cvt2(float lo, float hi) {
    __hip_bfloat162 h = __float22bfloat162_rn(make_float2(lo, hi));
    return *reinterpret_cast<unsigned*>(&h);   // v_cvt_pk_bf16_f32
}

// XOR swizzle within [row][64 bf16] (128B row stride); same bijection write+read.
__device__ __forceinline__ int swz(int row, int col_b) {
    return row * 128 + (col_b ^ ((row & 7) << 4));
}

__global__ __launch_bounds__(512)
void moe_fused(const float* __restrict__ inp,
               const int* __restrict__ gate,
               const float* __restrict__ weight,
               float* __restrict__ out) {
    // bijective XCD-chunk swizzle (768 blocks, 8 XCDs, 96/chunk): XCD k owns
    // experts [4k,4k+4) -> W panels + token rows pinned in that L2.
    const int bid = blockIdx.x;
    const int swb = (bid & 7) * (NWG / 8) + (bid >> 3);
    const int nb    = swb & 7;
    const int y     = swb >> 3;          // 0..95
    const int e     = y / 3;
    const int local = y - e * 3;

    __shared__ __align__(16) unsigned char lds[2 * BUFB];  // 32KB double buffer
    __shared__ int srow[BM];
    __shared__ int chunkinfo[NCHUNK];

    const int tid  = threadIdx.x;
    const int lane = tid & 63;
    const int wid  = tid >> 6;           // 0..7

    // staging map (16B granule): thread covers row tid>>3 (0..63) at float col
    // (tid&7)*8 -- one 16B A-slot and one 16B W-slot after cvt.
    const int srow_r = tid >> 3;         // 0..63
    const int c8     = (tid & 7) * 8;    // float offset of first float4
    const int nblk   = nb * BN;
    const float* wbase = weight + (size_t)e * (NF * KF) + (size_t)nblk * KF;

    float4 ra[2], rw[2];                 // one row-slot each: two float4s

    // ---- W tile-0 issued BEFORE prep: only needs e; latency hides under prep ----
    rw[0] = *(const float4*)(wbase + (size_t)srow_r * KF + c8);
    rw[1] = *(const float4*)(wbase + (size_t)srow_r * KF + c8 + 4);
    asm volatile("" ::: "memory");       // pin: issue now, don't sink into prep

    // ---- self-prep (512-thread): int4 gate loads + 8-bit mask + segment scan ----
    // thread owns gates [tid*8, tid*8+8), all inside chunk tid>>3
    int4 gv[2];
#pragma unroll
    for (int j = 0; j < 2; ++j)
        gv[j] = ((const int4*)gate)[tid * 2 + j];

    unsigned mask = 0;
#pragma unroll
    for (int j = 0; j < 2; ++j) {
        if (gv[j].x == e) mask |= 1u << (j * 4 + 0);
        if (gv[j].y == e) mask |= 1u << (j * 4 + 1);
        if (gv[j].z == e) mask |= 1u << (j * 4 + 2);
        if (gv[j].w == e) mask |= 1u << (j * 4 + 3);
    }
    const int cnt = __popc(mask);

    // inclusive scan over the 8 threads of this chunk (lanes grouped by 8)
    int xs = cnt;
    {
        int u = __shfl_up(xs, 1, 8); if ((lane & 7) >= 1) xs += u;
        u     = __shfl_up(xs, 2, 8); if ((lane & 7) >= 2) xs += u;
        u     = __shfl_up(xs, 4, 8); if ((lane & 7) >= 4) xs += u;
    }
    const int pre = xs - cnt;            // exclusive prefix within chunk
    if ((lane & 7) == 7) chunkinfo[tid >> 3] = xs;   // chunk total
    if (tid < BM) srow[tid] = -1;
    __syncthreads();                     // barrier 1: chunk counts + srow init

    // per-wave redundant scan of all 64 chunk counts (no cross-wave exchange)
    int cc = chunkinfo[lane];
    int x  = cc;
#pragma unroll
    for (int d = 1; d < 64; d <<= 1) {
        int u = __shfl_up(x, d, 64);
        if (lane >= d) x += u;
    }
    const int excl  = x - cc;            // lane l holds exclusive base of chunk l
    const int total = __shfl(x, 63, 64);

    // shfl with ALL lanes active (r18 bug fix); source lane = wid*8+(lane>>3),
    // valid 0..63 within this wave (each wave holds the full redundant scan).
    const int chunkbase = __shfl(excl, tid >> 3, 64);

    const int m0 = local * BM;
    if (m0 >= total) return;             // block-uniform exit (no barrier pending)

    // scatter: rank = own-chunk base + within-chunk prefix + intra-thread order
    if (mask) {
        int rr = chunkbase + pre;
        unsigned mm = mask;
        while (mm) {
            int j = __ffs(mm) - 1;
            mm &= mm - 1;
            if (rr >= m0 && rr < m0 + BM)
                srow[rr - m0] = tid * 8 + j;
            ++rr;
        }
    }
    __syncthreads();                     // barrier 2: srow ready

    const int wm = wid & 3;              // 4 m-quarters (16 rows)
    const int wn = wid >> 2;             // 2 n-halves (32 cols)

    const int arow0 = srow[srow_r];
    // clamp pad rows to row 0: real data, outputs never stored (r14-validated)
    const float* ap = inp + (size_t)(arow0 < 0 ? 0 : arow0) * KF + c8;

#define LOADA(T) do { const int k0 = (T) * BK;                                       \
    ra[0] = *(const float4*)(ap + k0);                                               \
    ra[1] = *(const float4*)(ap + k0 + 4); } while (0)

#define LOADW(T) do { const int k0 = (T) * BK;                                       \
    rw[0] = *(const float4*)(wbase + (size_t)srow_r * KF + k0 + c8);                 \
    rw[1] = *(const float4*)(wbase + (size_t)srow_r * KF + k0 + c8 + 4); } while (0)

#define WRITE_TILE(B) do { const int cb = (tid & 7) * 16;                            \
    unsigned char* Lb = lds + (B) * BUFB;                                            \
    { uint4 p = make_uint4(cvt2(ra[0].x, ra[0].y), cvt2(ra[0].z, ra[0].w),           \
                           cvt2(ra[1].x, ra[1].y), cvt2(ra[1].z, ra[1].w));          \
      *(uint4*)(Lb + swz(srow_r, cb)) = p; }                                         \
    { uint4 p = make_uint4(cvt2(rw[0].x, rw[0].y), cvt2(rw[0].z, rw[0].w),           \
                           cvt2(rw[1].x, rw[1].y), cvt2(rw[1].z, rw[1].w));          \
      *(uint4*)(Lb + 8192 + swz(srow_r, cb)) = p; } } while (0)

    f32x4 acc[2];
    acc[0] = (f32x4)(0.f);
    acc[1] = (f32x4)(0.f);

#define COMPUTE(B) do { const unsigned char* Lb = lds + (B) * BUFB;                  \
    _Pragma("unroll") for (int kk = 0; kk < 2; ++kk) {                               \
        const int kb = kk * 64 + 16 * (lane >> 4);                                   \
        int rA = wm * 16 + (lane & 15);                                              \
        bf16x8 af = *(const bf16x8*)(Lb + swz(rA, kb));                              \
        bf16x8 bfr[2];                                                               \
        _Pragma("unroll") for (int ni = 0; ni < 2; ++ni) {                           \
            int r = wn * 32 + ni * 16 + (lane & 15);                                 \
            bfr[ni] = *(const bf16x8*)(Lb + 8192 + swz(r, kb)); }                    \
        _Pragma("unroll") for (int ni = 0; ni < 2; ++ni)                             \
            acc[ni] = __builtin_amdgcn_mfma_f32_16x16x32_bf16(                       \
                af, bfr[ni], acc[ni], 0, 0, 0); } } while (0)

    // ---- double-buffered K-loop: ONE drain+barrier per iteration (r24 schedule;
    //      race-free: reads of buf X drain at iter t's barrier, next write to X
    //      is after it) ----
    LOADA(0);                            // W tile 0 in flight since kernel entry
    asm volatile("" ::: "memory");
    WRITE_TILE(0);                       // vmcnt waits tile-0 loads only
    asm volatile("s_waitcnt lgkmcnt(0)" ::: "memory");
    __builtin_amdgcn_s_barrier();        // buf0 ready

    for (int t = 0; t < NKT; ++t) {
        if (t + 1 < NKT) {
            LOADA(t + 1);                // issue early: COMPUTE covers latency
            LOADW(t + 1);
            asm volatile("" ::: "memory");  // PIN: loads may not sink below
        }
        COMPUTE(t & 1);                  // reads buf[cur]
        if (t + 1 < NKT) {
            WRITE_TILE((t + 1) & 1);     // disjoint buf: overlaps MFMA stream
            asm volatile("s_waitcnt lgkmcnt(0)" ::: "memory");  // reads+writes
            __builtin_amdgcn_s_barrier();
        }
    }
#undef LOADA
#undef LOADW
#undef WRITE_TILE
#undef COMPUTE

    // ---- epilogue: D frag col=lane&15 (n), row=(lane>>4)*4+q (m) ----
#pragma unroll
    for (int q = 0; q < 4; ++q) {
        int m = wm * 16 + (lane >> 4) * 4 + q;
        int row = srow[m];
        if (row >= 0) {
#pragma unroll
            for (int ni = 0; ni < 2; ++ni)
                out[(size_t)row * NF + nblk + wn * 32 + ni * 16 + (lane & 15)]
                    = acc[ni][q];
        }
    }
}

extern "C" void kernel_launch(void* const* d_in, const int* in_sizes, int n_in,
                              void* d_out, int out_size, void* d_ws, size_t ws_size,
                              hipStream_t stream) {
    const float* inp    = (const float*)d_in[0];
    const int*   gate   = (const int*)d_in[1];
    const float* weight = (const float*)d_in[2];
    float*       out    = (float*)d_out;

    moe_fused<<<NWG, 512, 0, stream>>>(inp, gate, weight, out);
}

// Round 27
// 17.294 us; speedup vs baseline: 1.1617x; 1.0803x over previous
//
#include <hip/hip_runtime.h>
#include <hip/hip_bf16.h>

// MoE: out[b] = inp[b] @ weight[gate[b]].T
// inp: [4096,512] f32, gate: [4096] int, weight: [32,512,512] f32, out: [4096,512] f32
// Round 27: r26 (best, 18.68us) with the load issue moved AFTER WRITE:
//   old: [loads(t+1); COMPUTE(t); WRITE(t+1); drain; barrier]
//   new: [COMPUTE(t); WRITE(t+1); loads(t+2); drain; barrier]
// At WRITE time the only outstanding loads are the ones it consumes, issued a
// FULL iteration earlier (cover = barrier+COMPUTE+WRITE ~500cy+) -> its vmcnt
// wait is ~free. New loads are issued after the consuming ds_writes, so no
// drain ever waits on them (r12's poison avoided); register WAR is handled by
// compiler renaming (+~16 VGPR transient bank). Drain+barrier placement is
// byte-identical to r24/r26 -> same race-freedom proof.
// All else r26-verbatim: 512thr/8 waves, 64x64x64 double-buffer, mask prep,
// W tile-0 pre-prep issue, 16B ds_writes, XOR swizzle, TMAX=3/grid 768.

#define NE     32
#define NBATCH 4096
#define KF     512
#define NF     512
#define BM     64
#define BN     64
#define BK     64
#define NKT    (KF / BK)     // 8
#define TMAX   3
#define NCHUNK 64
#define NWG    (8 * NE * TMAX)  // 768, %8==0 -> bijective XCD swizzle
#define BUFB   ((BM + BN) * BK * 2)  // 16KB per buffer

typedef __attribute__((ext_vector_type(8))) short bf16x8;
typedef __attribute__((ext_vector_type(4))) float f32x4;

__device__ __forceinline__ unsigned cvt2(float lo, float hi) {
    __hip_bfloat162 h = __float22bfloat162_rn(make_float2(lo, hi));
    return *reinterpret_cast<unsigned*>(&h);   // v_cvt_pk_bf16_f32
}

// XOR swizzle within [row][64 bf16] (128B row stride); same bijection write+read.
__device__ __forceinline__ int swz(int row, int col_b) {
    return row * 128 + (col_b ^ ((row & 7) << 4));
}

__global__ __launch_bounds__(512)
void moe_fused(const float* __restrict__ inp,
               const int* __restrict__ gate,
               const float* __restrict__ weight,
               float* __restrict__ out) {
    // bijective XCD-chunk swizzle (768 blocks, 8 XCDs, 96/chunk): XCD k owns
    // experts [4k,4k+4) -> W panels + token rows pinned in that L2.
    const int bid = blockIdx.x;
    const int swb = (bid & 7) * (NWG / 8) + (bid >> 3);
    const int nb    = swb & 7;
    const int y     = swb >> 3;          // 0..95
    const int e     = y / 3;
    const int local = y - e * 3;

    __shared__ __align__(16) unsigned char lds[2 * BUFB];  // 32KB double buffer
    __shared__ int srow[BM];
    __shared__ int chunkinfo[NCHUNK];

    const int tid  = threadIdx.x;
    const int lane = tid & 63;
    const int wid  = tid >> 6;           // 0..7

    // staging map (16B granule): thread covers row tid>>3 (0..63) at float col
    // (tid&7)*8 -- one 16B A-slot and one 16B W-slot after cvt.
    const int srow_r = tid >> 3;         // 0..63
    const int c8     = (tid & 7) * 8;    // float offset of first float4
    const int nblk   = nb * BN;
    const float* wbase = weight + (size_t)e * (NF * KF) + (size_t)nblk * KF;

    float4 ra[2], rw[2];                 // one row-slot each: two float4s

    // ---- W tile-0 issued BEFORE prep: only needs e; latency hides under prep ----
    rw[0] = *(const float4*)(wbase + (size_t)srow_r * KF + c8);
    rw[1] = *(const float4*)(wbase + (size_t)srow_r * KF + c8 + 4);
    asm volatile("" ::: "memory");       // pin: issue now, don't sink into prep

    // ---- self-prep (512-thread): int4 gate loads + 8-bit mask + segment scan ----
    // thread owns gates [tid*8, tid*8+8), all inside chunk tid>>3
    int4 gv[2];
#pragma unroll
    for (int j = 0; j < 2; ++j)
        gv[j] = ((const int4*)gate)[tid * 2 + j];

    unsigned mask = 0;
#pragma unroll
    for (int j = 0; j < 2; ++j) {
        if (gv[j].x == e) mask |= 1u << (j * 4 + 0);
        if (gv[j].y == e) mask |= 1u << (j * 4 + 1);
        if (gv[j].z == e) mask |= 1u << (j * 4 + 2);
        if (gv[j].w == e) mask |= 1u << (j * 4 + 3);
    }
    const int cnt = __popc(mask);

    // inclusive scan over the 8 threads of this chunk (lanes grouped by 8)
    int xs = cnt;
    {
        int u = __shfl_up(xs, 1, 8); if ((lane & 7) >= 1) xs += u;
        u     = __shfl_up(xs, 2, 8); if ((lane & 7) >= 2) xs += u;
        u     = __shfl_up(xs, 4, 8); if ((lane & 7) >= 4) xs += u;
    }
    const int pre = xs - cnt;            // exclusive prefix within chunk
    if ((lane & 7) == 7) chunkinfo[tid >> 3] = xs;   // chunk total
    if (tid < BM) srow[tid] = -1;
    __syncthreads();                     // barrier 1: chunk counts + srow init

    // per-wave redundant scan of all 64 chunk counts (no cross-wave exchange)
    int cc = chunkinfo[lane];
    int x  = cc;
#pragma unroll
    for (int d = 1; d < 64; d <<= 1) {
        int u = __shfl_up(x, d, 64);
        if (lane >= d) x += u;
    }
    const int excl  = x - cc;            // lane l holds exclusive base of chunk l
    const int total = __shfl(x, 63, 64);

    // shfl with ALL lanes active (r18 bug fix); source lane = wid*8+(lane>>3),
    // valid 0..63 within this wave (each wave holds the full redundant scan).
    const int chunkbase = __shfl(excl, tid >> 3, 64);

    const int m0 = local * BM;
    if (m0 >= total) return;             // block-uniform exit (no barrier pending)

    // scatter: rank = own-chunk base + within-chunk prefix + intra-thread order
    if (mask) {
        int rr = chunkbase + pre;
        unsigned mm = mask;
        while (mm) {
            int j = __ffs(mm) - 1;
            mm &= mm - 1;
            if (rr >= m0 && rr < m0 + BM)
                srow[rr - m0] = tid * 8 + j;
            ++rr;
        }
    }
    __syncthreads();                     // barrier 2: srow ready

    const int wm = wid & 3;              // 4 m-quarters (16 rows)
    const int wn = wid >> 2;             // 2 n-halves (32 cols)

    const int arow0 = srow[srow_r];
    // clamp pad rows to row 0: real data, outputs never stored (r14-validated)
    const float* ap = inp + (size_t)(arow0 < 0 ? 0 : arow0) * KF + c8;

#define LOADA(T) do { const int k0 = (T) * BK;                                       \
    ra[0] = *(const float4*)(ap + k0);                                               \
    ra[1] = *(const float4*)(ap + k0 + 4); } while (0)

#define LOADW(T) do { const int k0 = (T) * BK;                                       \
    rw[0] = *(const float4*)(wbase + (size_t)srow_r * KF + k0 + c8);                 \
    rw[1] = *(const float4*)(wbase + (size_t)srow_r * KF + k0 + c8 + 4); } while (0)

#define WRITE_TILE(B) do { const int cb = (tid & 7) * 16;                            \
    unsigned char* Lb = lds + (B) * BUFB;                                            \
    { uint4 p = make_uint4(cvt2(ra[0].x, ra[0].y), cvt2(ra[0].z, ra[0].w),           \
                           cvt2(ra[1].x, ra[1].y), cvt2(ra[1].z, ra[1].w));          \
      *(uint4*)(Lb + swz(srow_r, cb)) = p; }                                         \
    { uint4 p = make_uint4(cvt2(rw[0].x, rw[0].y), cvt2(rw[0].z, rw[0].w),           \
                           cvt2(rw[1].x, rw[1].y), cvt2(rw[1].z, rw[1].w));          \
      *(uint4*)(Lb + 8192 + swz(srow_r, cb)) = p; } } while (0)

    f32x4 acc[2];
    acc[0] = (f32x4)(0.f);
    acc[1] = (f32x4)(0.f);

#define COMPUTE(B) do { const unsigned char* Lb = lds + (B) * BUFB;                  \
    _Pragma("unroll") for (int kk = 0; kk < 2; ++kk) {                               \
        const int kb = kk * 64 + 16 * (lane >> 4);                                   \
        int rA = wm * 16 + (lane & 15);                                              \
        bf16x8 af = *(const bf16x8*)(Lb + swz(rA, kb));                              \
        bf16x8 bfr[2];                                                               \
        _Pragma("unroll") for (int ni = 0; ni < 2; ++ni) {                           \
            int r = wn * 32 + ni * 16 + (lane & 15);                                 \
            bfr[ni] = *(const bf16x8*)(Lb + 8192 + swz(r, kb)); }                    \
        _Pragma("unroll") for (int ni = 0; ni < 2; ++ni)                             \
            acc[ni] = __builtin_amdgcn_mfma_f32_16x16x32_bf16(                       \
                af, bfr[ni], acc[ni], 0, 0, 0); } } while (0)

    // ---- double-buffered K-loop, loads issued AFTER the consuming WRITE ----
    // prologue: stage tile 0; then issue tile-1 loads (cover: drain+barrier+COMPUTE)
    LOADA(0);                            // W tile 0 in flight since kernel entry
    asm volatile("" ::: "memory");
    WRITE_TILE(0);                       // vmcnt drains tile-0 loads only
    LOADA(1);
    LOADW(1);
    asm volatile("" ::: "memory");       // pin above the drain+barrier
    asm volatile("s_waitcnt lgkmcnt(0)" ::: "memory");
    __builtin_amdgcn_s_barrier();        // buf0 ready (tile-1 loads in flight)

    for (int t = 0; t < NKT; ++t) {
        COMPUTE(t & 1);                  // reads buf[cur]
        if (t + 1 < NKT) {
            WRITE_TILE((t + 1) & 1);     // regs loaded >= 1 full iter ago: vmcnt ~free
            if (t + 2 < NKT) {
                LOADA(t + 2);            // issued AFTER consuming ds_writes: never
                LOADW(t + 2);            // in front of a drain (r12 poison avoided)
                asm volatile("" ::: "memory");
            }
            asm volatile("s_waitcnt lgkmcnt(0)" ::: "memory");  // reads+writes
            __builtin_amdgcn_s_barrier();
        }
    }
#undef LOADA
#undef LOADW
#undef WRITE_TILE
#undef COMPUTE

    // ---- epilogue: D frag col=lane&15 (n), row=(lane>>4)*4+q (m) ----
#pragma unroll
    for (int q = 0; q < 4; ++q) {
        int m = wm * 16 + (lane >> 4) * 4 + q;
        int row = srow[m];
        if (row >= 0) {
#pragma unroll
            for (int ni = 0; ni < 2; ++ni)
                out[(size_t)row * NF + nblk + wn * 32 + ni * 16 + (lane & 15)]
                    = acc[ni][q];
        }
    }
}

extern "C" void kernel_launch(void* const* d_in, const int* in_sizes, int n_in,
                              void* d_out, int out_size, void* d_ws, size_t ws_size,
                              hipStream_t stream) {
    const float* inp    = (const float*)d_in[0];
    const int*   gate   = (const int*)d_in[1];
    const float* weight = (const float*)d_in[2];
    float*       out    = (float*)d_out;

    moe_fused<<<NWG, 512, 0, stream>>>(inp, gate, weight, out);
}

// Round 28
// 17.015 us; speedup vs baseline: 1.1808x; 1.0164x over previous
//
#include <hip/hip_runtime.h>
#include <hip/hip_bf16.h>

// MoE: out[b] = inp[b] @ weight[gate[b]].T
// inp: [4096,512] f32, gate: [4096] int, weight: [32,512,512] f32, out: [4096,512] f32
// Round 28: r27 (best, 17.29us) + DEPTH-2 register banks at the post-WRITE issue
// point: loads(t+3) issue after WRITE(t+1) -> WRITE(t+1) consumes loads issued
// TWO full iterations earlier (~800cy cover, enough for L2-miss W streams at
// ~900cy), while no load ever sits in front of a drain (r12 poison avoided --
// issue point is after the consuming ds_writes). Static bank indices via full
// unroll of the NKT=8 loop (rule #20). +16 VGPR.
// All else r27-verbatim: 512thr/8 waves, 64x64x64 double-buffer, one
// drain+barrier/iter (race-free proof unchanged), mask prep, W tile-0 pre-prep
// issue, 16B ds_writes, XOR swizzle, TMAX=3/grid 768, clamped pad rows.

#define NE     32
#define NBATCH 4096
#define KF     512
#define NF     512
#define BM     64
#define BN     64
#define BK     64
#define NKT    (KF / BK)     // 8
#define TMAX   3
#define NCHUNK 64
#define NWG    (8 * NE * TMAX)  // 768, %8==0 -> bijective XCD swizzle
#define BUFB   ((BM + BN) * BK * 2)  // 16KB per buffer

typedef __attribute__((ext_vector_type(8))) short bf16x8;
typedef __attribute__((ext_vector_type(4))) float f32x4;

__device__ __forceinline__ unsigned cvt2(float lo, float hi) {
    __hip_bfloat162 h = __float22bfloat162_rn(make_float2(lo, hi));
    return *reinterpret_cast<unsigned*>(&h);   // v_cvt_pk_bf16_f32
}

// XOR swizzle within [row][64 bf16] (128B row stride); same bijection write+read.
__device__ __forceinline__ int swz(int row, int col_b) {
    return row * 128 + (col_b ^ ((row & 7) << 4));
}

__global__ __launch_bounds__(512)
void moe_fused(const float* __restrict__ inp,
               const int* __restrict__ gate,
               const float* __restrict__ weight,
               float* __restrict__ out) {
    // bijective XCD-chunk swizzle (768 blocks, 8 XCDs, 96/chunk): XCD k owns
    // experts [4k,4k+4) -> W panels + token rows pinned in that L2.
    const int bid = blockIdx.x;
    const int swb = (bid & 7) * (NWG / 8) + (bid >> 3);
    const int nb    = swb & 7;
    const int y     = swb >> 3;          // 0..95
    const int e     = y / 3;
    const int local = y - e * 3;

    __shared__ __align__(16) unsigned char lds[2 * BUFB];  // 32KB double buffer
    __shared__ int srow[BM];
    __shared__ int chunkinfo[NCHUNK];

    const int tid  = threadIdx.x;
    const int lane = tid & 63;
    const int wid  = tid >> 6;           // 0..7

    // staging map (16B granule): thread covers row tid>>3 (0..63) at float col
    // (tid&7)*8 -- one 16B A-slot and one 16B W-slot after cvt.
    const int srow_r = tid >> 3;         // 0..63
    const int c8     = (tid & 7) * 8;    // float offset of first float4
    const int nblk   = nb * BN;
    const float* wbase = weight + (size_t)e * (NF * KF) + (size_t)nblk * KF;

    float4 ra[2][2], rw[2][2];           // [bank][half]; bank = tile & 1

    // ---- W tile-0 issued BEFORE prep: only needs e; latency hides under prep ----
    rw[0][0] = *(const float4*)(wbase + (size_t)srow_r * KF + c8);
    rw[0][1] = *(const float4*)(wbase + (size_t)srow_r * KF + c8 + 4);
    asm volatile("" ::: "memory");       // pin: issue now, don't sink into prep

    // ---- self-prep (512-thread): int4 gate loads + 8-bit mask + segment scan ----
    // thread owns gates [tid*8, tid*8+8), all inside chunk tid>>3
    int4 gv[2];
#pragma unroll
    for (int j = 0; j < 2; ++j)
        gv[j] = ((const int4*)gate)[tid * 2 + j];

    unsigned mask = 0;
#pragma unroll
    for (int j = 0; j < 2; ++j) {
        if (gv[j].x == e) mask |= 1u << (j * 4 + 0);
        if (gv[j].y == e) mask |= 1u << (j * 4 + 1);
        if (gv[j].z == e) mask |= 1u << (j * 4 + 2);
        if (gv[j].w == e) mask |= 1u << (j * 4 + 3);
    }
    const int cnt = __popc(mask);

    // inclusive scan over the 8 threads of this chunk (lanes grouped by 8)
    int xs = cnt;
    {
        int u = __shfl_up(xs, 1, 8); if ((lane & 7) >= 1) xs += u;
        u     = __shfl_up(xs, 2, 8); if ((lane & 7) >= 2) xs += u;
        u     = __shfl_up(xs, 4, 8); if ((lane & 7) >= 4) xs += u;
    }
    const int pre = xs - cnt;            // exclusive prefix within chunk
    if ((lane & 7) == 7) chunkinfo[tid >> 3] = xs;   // chunk total
    if (tid < BM) srow[tid] = -1;
    __syncthreads();                     // barrier 1: chunk counts + srow init

    // per-wave redundant scan of all 64 chunk counts (no cross-wave exchange)
    int cc = chunkinfo[lane];
    int x  = cc;
#pragma unroll
    for (int d = 1; d < 64; d <<= 1) {
        int u = __shfl_up(x, d, 64);
        if (lane >= d) x += u;
    }
    const int excl  = x - cc;            // lane l holds exclusive base of chunk l
    const int total = __shfl(x, 63, 64);

    // shfl with ALL lanes active (r18 bug fix); source lane = wid*8+(lane>>3),
    // valid 0..63 within this wave (each wave holds the full redundant scan).
    const int chunkbase = __shfl(excl, tid >> 3, 64);

    const int m0 = local * BM;
    if (m0 >= total) return;             // block-uniform exit (no barrier pending)

    // scatter: rank = own-chunk base + within-chunk prefix + intra-thread order
    if (mask) {
        int rr = chunkbase + pre;
        unsigned mm = mask;
        while (mm) {
            int j = __ffs(mm) - 1;
            mm &= mm - 1;
            if (rr >= m0 && rr < m0 + BM)
                srow[rr - m0] = tid * 8 + j;
            ++rr;
        }
    }
    __syncthreads();                     // barrier 2: srow ready

    const int wm = wid & 3;              // 4 m-quarters (16 rows)
    const int wn = wid >> 2;             // 2 n-halves (32 cols)

    const int arow0 = srow[srow_r];
    // clamp pad rows to row 0: real data, outputs never stored (r14-validated)
    const float* ap = inp + (size_t)(arow0 < 0 ? 0 : arow0) * KF + c8;

#define LOADA(B, T) do { const int k0 = (T) * BK;                                    \
    ra[B][0] = *(const float4*)(ap + k0);                                            \
    ra[B][1] = *(const float4*)(ap + k0 + 4); } while (0)

#define LOADW(B, T) do { const int k0 = (T) * BK;                                    \
    rw[B][0] = *(const float4*)(wbase + (size_t)srow_r * KF + k0 + c8);              \
    rw[B][1] = *(const float4*)(wbase + (size_t)srow_r * KF + k0 + c8 + 4); } while (0)

#define WRITE_TILE(B) do { const int cb = (tid & 7) * 16;                            \
    unsigned char* Lb = lds + (B) * BUFB;                                            \
    { uint4 p = make_uint4(cvt2(ra[B][0].x, ra[B][0].y), cvt2(ra[B][0].z, ra[B][0].w), \
                           cvt2(ra[B][1].x, ra[B][1].y), cvt2(ra[B][1].z, ra[B][1].w)); \
      *(uint4*)(Lb + swz(srow_r, cb)) = p; }                                         \
    { uint4 p = make_uint4(cvt2(rw[B][0].x, rw[B][0].y), cvt2(rw[B][0].z, rw[B][0].w), \
                           cvt2(rw[B][1].x, rw[B][1].y), cvt2(rw[B][1].z, rw[B][1].w)); \
      *(uint4*)(Lb + 8192 + swz(srow_r, cb)) = p; } } while (0)

    f32x4 acc[2];
    acc[0] = (f32x4)(0.f);
    acc[1] = (f32x4)(0.f);

#define COMPUTE(B) do { const unsigned char* Lb = lds + (B) * BUFB;                  \
    _Pragma("unroll") for (int kk = 0; kk < 2; ++kk) {                               \
        const int kb = kk * 64 + 16 * (lane >> 4);                                   \
        int rA = wm * 16 + (lane & 15);                                              \
        bf16x8 af = *(const bf16x8*)(Lb + swz(rA, kb));                              \
        bf16x8 bfr[2];                                                               \
        _Pragma("unroll") for (int ni = 0; ni < 2; ++ni) {                           \
            int r = wn * 32 + ni * 16 + (lane & 15);                                 \
            bfr[ni] = *(const bf16x8*)(Lb + 8192 + swz(r, kb)); }                    \
        _Pragma("unroll") for (int ni = 0; ni < 2; ++ni)                             \
            acc[ni] = __builtin_amdgcn_mfma_f32_16x16x32_bf16(                       \
                af, bfr[ni], acc[ni], 0, 0, 0); } } while (0)

    // ---- depth-2 double-buffered K-loop, loads AFTER the consuming WRITE ----
    // bank = tile & 1; lds buf = tile & 1 (same parity).
    // prologue: tile-0 staged; tiles 1,2 issued (bank1, bank0-after-free)
    LOADA(0, 0);                         // bank0 (W tile-0 already in flight)
    asm volatile("" ::: "memory");
    WRITE_TILE(0);                       // consumes bank0 (vmcnt waits tile-0 only)
    LOADA(1, 1); LOADW(1, 1);            // bank1 -> used at WRITE(1), iter 0
    LOADA(0, 2); LOADW(0, 2);            // bank0 (freed) -> used at WRITE(2), iter 1
    asm volatile("" ::: "memory");       // pin above drain+barrier
    asm volatile("s_waitcnt lgkmcnt(0)" ::: "memory");
    __builtin_amdgcn_s_barrier();        // buf0 ready; tiles 1,2 in flight

#pragma unroll
    for (int t = 0; t < NKT; ++t) {      // full unroll: static bank indices
        COMPUTE(t & 1);                  // reads lds buf[cur]
        if (t + 1 < NKT) {
            WRITE_TILE((t + 1) & 1);     // consumes bank loaded 2 iters ago
            if (t + 3 < NKT) {
                LOADA((t + 3) & 1, t + 3);  // bank just freed by this WRITE;
                LOADW((t + 3) & 1, t + 3);  // never in front of a drain
                asm volatile("" ::: "memory");
            }
            asm volatile("s_waitcnt lgkmcnt(0)" ::: "memory");  // reads+writes
            __builtin_amdgcn_s_barrier();
        }
    }
#undef LOADA
#undef LOADW
#undef WRITE_TILE
#undef COMPUTE

    // ---- epilogue: D frag col=lane&15 (n), row=(lane>>4)*4+q (m) ----
#pragma unroll
    for (int q = 0; q < 4; ++q) {
        int m = wm * 16 + (lane >> 4) * 4 + q;
        int row = srow[m];
        if (row >= 0) {
#pragma unroll
            for (int ni = 0; ni < 2; ++ni)
                out[(size_t)row * NF + nblk + wn * 32 + ni * 16 + (lane & 15)]
                    = acc[ni][q];
        }
    }
}

extern "C" void kernel_launch(void* const* d_in, const int* in_sizes, int n_in,
                              void* d_out, int out_size, void* d_ws, size_t ws_size,
                              hipStream_t stream) {
    const float* inp    = (const float*)d_in[0];
    const int*   gate   = (const int*)d_in[1];
    const float* weight = (const float*)d_in[2];
    float*       out    = (float*)d_out;

    moe_fused<<<NWG, 512, 0, stream>>>(inp, gate, weight, out);
}